// Round 1
// baseline (5437.053 us; speedup 1.0000x reference)
//
#include <hip/hip_runtime.h>

#ifndef OUT_DIM
#define OUT_DIM 128
#endif

// Stage 1: XW[feat_rows[i], :] += feat_vals[i] * W[feat_cols[i], :]
// 32 threads per nnz; each thread owns one float4 (4 feats) of the 128-wide row.
__global__ void xw_scatter_kernel(const int* __restrict__ rows,
                                  const int* __restrict__ cols,
                                  const float* __restrict__ vals,
                                  const float* __restrict__ W,
                                  float* __restrict__ XW,
                                  int nnz) {
    int t = blockIdx.x * blockDim.x + threadIdx.x;
    int i = t >> 5;          // nnz index
    int f4 = t & 31;         // which float4 of 32 (128 floats / 4)
    if (i >= nnz) return;
    int r = rows[i];
    int c = cols[i];
    float v = vals[i];
    const float4 w = ((const float4*)(W + (size_t)c * OUT_DIM))[f4];
    float* dst = XW + (size_t)r * OUT_DIM + (size_t)f4 * 4;
    unsafeAtomicAdd(dst + 0, v * w.x);
    unsafeAtomicAdd(dst + 1, v * w.y);
    unsafeAtomicAdd(dst + 2, v * w.z);
    unsafeAtomicAdd(dst + 3, v * w.w);
}

// Stage 2: out[adj_rows[e], :] += adj_vals[e] * XW[adj_cols[e], :]
__global__ void agg_scatter_kernel(const int* __restrict__ rows,
                                   const int* __restrict__ cols,
                                   const float* __restrict__ vals,
                                   const float* __restrict__ XW,
                                   float* __restrict__ out,
                                   int nnz) {
    int t = blockIdx.x * blockDim.x + threadIdx.x;
    int e = t >> 5;
    int f4 = t & 31;
    if (e >= nnz) return;
    int dr = rows[e];
    int sc = cols[e];
    float v = vals[e];
    const float4 x = ((const float4*)(XW + (size_t)sc * OUT_DIM))[f4];
    float* dst = out + (size_t)dr * OUT_DIM + (size_t)f4 * 4;
    unsafeAtomicAdd(dst + 0, v * x.x);
    unsafeAtomicAdd(dst + 1, v * x.y);
    unsafeAtomicAdd(dst + 2, v * x.z);
    unsafeAtomicAdd(dst + 3, v * x.w);
}

// Stage 3: relu in place (float4 grid-stride)
__global__ void relu_kernel(float4* __restrict__ p, int n4) {
    int t = blockIdx.x * blockDim.x + threadIdx.x;
    int stride = gridDim.x * blockDim.x;
    for (int i = t; i < n4; i += stride) {
        float4 v = p[i];
        v.x = fmaxf(v.x, 0.0f);
        v.y = fmaxf(v.y, 0.0f);
        v.z = fmaxf(v.z, 0.0f);
        v.w = fmaxf(v.w, 0.0f);
        p[i] = v;
    }
}

extern "C" void kernel_launch(void* const* d_in, const int* in_sizes, int n_in,
                              void* d_out, int out_size, void* d_ws, size_t ws_size,
                              hipStream_t stream) {
    const int*   feat_rows = (const int*)d_in[0];
    const int*   feat_cols = (const int*)d_in[1];
    const float* feat_vals = (const float*)d_in[2];
    const int*   adj_rows  = (const int*)d_in[3];
    const int*   adj_cols  = (const int*)d_in[4];
    const float* adj_vals  = (const float*)d_in[5];
    const float* W         = (const float*)d_in[6];
    float*       out       = (float*)d_out;

    const int nnz_x   = in_sizes[0];
    const int nnz_a   = in_sizes[3];
    const int n_nodes = out_size / OUT_DIM;

    float* XW = (float*)d_ws;  // [n_nodes, 128] fp32 = 51.2 MB

    // Zero accumulation buffers (ws/out are poisoned 0xAA before every launch).
    hipMemsetAsync(XW, 0, (size_t)n_nodes * OUT_DIM * sizeof(float), stream);
    hipMemsetAsync(out, 0, (size_t)out_size * sizeof(float), stream);

    const int block = 256;

    // Stage 1
    {
        long long total = (long long)nnz_x * 32;
        int grid = (int)((total + block - 1) / block);
        xw_scatter_kernel<<<grid, block, 0, stream>>>(feat_rows, feat_cols, feat_vals,
                                                      W, XW, nnz_x);
    }
    // Stage 2
    {
        long long total = (long long)nnz_a * 32;
        int grid = (int)((total + block - 1) / block);
        agg_scatter_kernel<<<grid, block, 0, stream>>>(adj_rows, adj_cols, adj_vals,
                                                       XW, out, nnz_a);
    }
    // Stage 3: relu
    {
        int n4 = out_size / 4;
        int grid = 1024;
        relu_kernel<<<grid, block, 0, stream>>>((float4*)out, n4);
    }
}

// Round 2
// 819.178 us; speedup vs baseline: 6.6372x; 6.6372x over previous
//
#include <hip/hip_runtime.h>

#define OUT_DIM 128
#define SCAN_BLOCK 1024

// ---------- CSR build ----------

__global__ void hist_kernel(const int* __restrict__ rows, int* __restrict__ cnt, int nnz) {
    int i = blockIdx.x * blockDim.x + threadIdx.x;
    if (i < nnz) atomicAdd(&cnt[rows[i]], 1);
}

// Per-block sums of counts -> partial[b]
__global__ void scan_partial_kernel(const int* __restrict__ cnt, int* __restrict__ partial, int n) {
    __shared__ int s[SCAN_BLOCK];
    int tid = threadIdx.x;
    int gid = blockIdx.x * SCAN_BLOCK + tid;
    s[tid] = (gid < n) ? cnt[gid] : 0;
    __syncthreads();
    for (int off = SCAN_BLOCK / 2; off > 0; off >>= 1) {
        if (tid < off) s[tid] += s[tid + off];
        __syncthreads();
    }
    if (tid == 0) partial[blockIdx.x] = s[0];
}

// Exclusive scan of the (<=1024) block partials, in place. Single block.
__global__ void scan_top_kernel(int* __restrict__ partial, int nb) {
    __shared__ int s[SCAN_BLOCK];
    int tid = threadIdx.x;
    int v = (tid < nb) ? partial[tid] : 0;
    s[tid] = v;
    __syncthreads();
    for (int off = 1; off < SCAN_BLOCK; off <<= 1) {
        int t = (tid >= off) ? s[tid - off] : 0;
        __syncthreads();
        s[tid] += t;
        __syncthreads();
    }
    if (tid < nb) partial[tid] = s[tid] - v;  // exclusive
}

// Block-local exclusive scan + block offset. cnt_cursor is read as counts and
// overwritten with the exclusive prefix (becomes the scatter cursor).
__global__ void scan_final_kernel(int* __restrict__ cnt_cursor, const int* __restrict__ partial,
                                  int* __restrict__ row_ptr, int n) {
    __shared__ int s[SCAN_BLOCK];
    int tid = threadIdx.x;
    int gid = blockIdx.x * SCAN_BLOCK + tid;
    int v = (gid < n) ? cnt_cursor[gid] : 0;
    s[tid] = v;
    __syncthreads();
    for (int off = 1; off < SCAN_BLOCK; off <<= 1) {
        int t = (tid >= off) ? s[tid - off] : 0;
        __syncthreads();
        s[tid] += t;
        __syncthreads();
    }
    int excl = s[tid] - v + partial[blockIdx.x];
    if (gid < n) {
        row_ptr[gid] = excl;
        cnt_cursor[gid] = excl;
    }
    if (gid == n - 1) row_ptr[n] = excl + v;
}

__global__ void scatter_kernel(const int* __restrict__ rows, int* __restrict__ cursor,
                               int* __restrict__ order, int nnz) {
    int i = blockIdx.x * blockDim.x + threadIdx.x;
    if (i < nnz) {
        int p = atomicAdd(&cursor[rows[i]], 1);
        order[p] = i;
    }
}

// ---------- Gather stages (no atomics; one 512B row write per node) ----------

// XW[n,:] = sum_j vals[e] * W[cols[e],:]   (32 lanes per node, float4 each)
__global__ void gather_xw_kernel(const int* __restrict__ row_ptr, const int* __restrict__ order,
                                 const int* __restrict__ cols, const float* __restrict__ vals,
                                 const float* __restrict__ W, float* __restrict__ XW, int n) {
    int t = blockIdx.x * blockDim.x + threadIdx.x;
    int node = t >> 5;
    int f4 = t & 31;
    if (node >= n) return;
    int start = row_ptr[node];
    int end = row_ptr[node + 1];
    float4 acc = {0.f, 0.f, 0.f, 0.f};
    const float4* W4 = (const float4*)W;
    for (int j = start; j < end; ++j) {
        int e = order[j];
        float v = vals[e];
        int c = cols[e];
        float4 w = W4[(size_t)c * 32 + f4];
        acc.x += v * w.x;
        acc.y += v * w.y;
        acc.z += v * w.z;
        acc.w += v * w.w;
    }
    ((float4*)XW)[(size_t)node * 32 + f4] = acc;
}

// out[n,:] = relu( sum_j vals[e] * XW[cols[e],:] )
__global__ void gather_agg_relu_kernel(const int* __restrict__ row_ptr, const int* __restrict__ order,
                                       const int* __restrict__ cols, const float* __restrict__ vals,
                                       const float* __restrict__ XW, float* __restrict__ out, int n) {
    int t = blockIdx.x * blockDim.x + threadIdx.x;
    int node = t >> 5;
    int f4 = t & 31;
    if (node >= n) return;
    int start = row_ptr[node];
    int end = row_ptr[node + 1];
    float4 acc = {0.f, 0.f, 0.f, 0.f};
    const float4* X4 = (const float4*)XW;
    for (int j = start; j < end; ++j) {
        int e = order[j];
        float v = vals[e];
        int c = cols[e];
        float4 x = X4[(size_t)c * 32 + f4];
        acc.x += v * x.x;
        acc.y += v * x.y;
        acc.z += v * x.z;
        acc.w += v * x.w;
    }
    acc.x = fmaxf(acc.x, 0.f);
    acc.y = fmaxf(acc.y, 0.f);
    acc.z = fmaxf(acc.z, 0.f);
    acc.w = fmaxf(acc.w, 0.f);
    ((float4*)out)[(size_t)node * 32 + f4] = acc;
}

extern "C" void kernel_launch(void* const* d_in, const int* in_sizes, int n_in,
                              void* d_out, int out_size, void* d_ws, size_t ws_size,
                              hipStream_t stream) {
    const int*   feat_rows = (const int*)d_in[0];
    const int*   feat_cols = (const int*)d_in[1];
    const float* feat_vals = (const float*)d_in[2];
    const int*   adj_rows  = (const int*)d_in[3];
    const int*   adj_cols  = (const int*)d_in[4];
    const float* adj_vals  = (const float*)d_in[5];
    const float* W         = (const float*)d_in[6];
    float*       out       = (float*)d_out;

    const int nnz_x   = in_sizes[0];
    const int nnz_a   = in_sizes[3];
    const int n_nodes = out_size / OUT_DIM;

    // ---- workspace layout ----
    char* p = (char*)d_ws;
    float* XW = (float*)p;                 p += (size_t)n_nodes * OUT_DIM * sizeof(float);
    int* A_row_ptr = (int*)p;              p += (size_t)(n_nodes + 1) * sizeof(int);
    int* X_row_ptr = (int*)p;              p += (size_t)(n_nodes + 1) * sizeof(int);
    int* A_cursor  = (int*)p;              p += (size_t)n_nodes * sizeof(int);
    int* X_cursor  = (int*)p;              p += (size_t)n_nodes * sizeof(int);
    int* A_order   = (int*)p;              p += (size_t)nnz_a * sizeof(int);
    int* X_order   = (int*)p;              p += (size_t)nnz_x * sizeof(int);
    int* A_partial = (int*)p;              p += (size_t)SCAN_BLOCK * sizeof(int);
    int* X_partial = (int*)p;              p += (size_t)SCAN_BLOCK * sizeof(int);

    const int block = 256;
    const int nb_scan = (n_nodes + SCAN_BLOCK - 1) / SCAN_BLOCK;
    const int grid_x = (nnz_x + block - 1) / block;
    const int grid_a = (nnz_a + block - 1) / block;

    // zero the count/cursor arrays (used as histogram targets)
    hipMemsetAsync(A_cursor, 0, (size_t)n_nodes * sizeof(int), stream);
    hipMemsetAsync(X_cursor, 0, (size_t)n_nodes * sizeof(int), stream);

    // histograms
    hist_kernel<<<grid_a, block, 0, stream>>>(adj_rows, A_cursor, nnz_a);
    hist_kernel<<<grid_x, block, 0, stream>>>(feat_rows, X_cursor, nnz_x);

    // scans -> row_ptr + cursor
    scan_partial_kernel<<<nb_scan, SCAN_BLOCK, 0, stream>>>(A_cursor, A_partial, n_nodes);
    scan_partial_kernel<<<nb_scan, SCAN_BLOCK, 0, stream>>>(X_cursor, X_partial, n_nodes);
    scan_top_kernel<<<1, SCAN_BLOCK, 0, stream>>>(A_partial, nb_scan);
    scan_top_kernel<<<1, SCAN_BLOCK, 0, stream>>>(X_partial, nb_scan);
    scan_final_kernel<<<nb_scan, SCAN_BLOCK, 0, stream>>>(A_cursor, A_partial, A_row_ptr, n_nodes);
    scan_final_kernel<<<nb_scan, SCAN_BLOCK, 0, stream>>>(X_cursor, X_partial, X_row_ptr, n_nodes);

    // scatter edge ids into CSR order
    scatter_kernel<<<grid_a, block, 0, stream>>>(adj_rows, A_cursor, A_order, nnz_a);
    scatter_kernel<<<grid_x, block, 0, stream>>>(feat_rows, X_cursor, X_order, nnz_x);

    // gather stages (no atomics)
    const int grid_gather = ((n_nodes * 32) + block - 1) / block;
    gather_xw_kernel<<<grid_gather, block, 0, stream>>>(X_row_ptr, X_order, feat_cols, feat_vals,
                                                        W, XW, n_nodes);
    gather_agg_relu_kernel<<<grid_gather, block, 0, stream>>>(A_row_ptr, A_order, adj_cols, adj_vals,
                                                              XW, out, n_nodes);
}

// Round 3
// 568.296 us; speedup vs baseline: 9.5673x; 1.4415x over previous
//
#include <hip/hip_runtime.h>
#include <hip/hip_fp16.h>

#define OUT_DIM 128
#define SCAN_BLOCK 1024

// ---------- combined CSR build (A rows at [0,n), X rows at [n,2n)) ----------

__global__ void hist2_kernel(const int* __restrict__ adj_rows, int nnz_a,
                             const int* __restrict__ feat_rows, int nnz_x,
                             int* __restrict__ cnt, int n_nodes) {
    int i = blockIdx.x * blockDim.x + threadIdx.x;
    if (i < nnz_a) {
        atomicAdd(&cnt[adj_rows[i]], 1);
    } else if (i < nnz_a + nnz_x) {
        atomicAdd(&cnt[n_nodes + feat_rows[i - nnz_a]], 1);
    }
}

__global__ void scan_partial_kernel(const int* __restrict__ cnt, int* __restrict__ partial, int n) {
    __shared__ int s[SCAN_BLOCK];
    int tid = threadIdx.x;
    int gid = blockIdx.x * SCAN_BLOCK + tid;
    s[tid] = (gid < n) ? cnt[gid] : 0;
    __syncthreads();
    for (int off = SCAN_BLOCK / 2; off > 0; off >>= 1) {
        if (tid < off) s[tid] += s[tid + off];
        __syncthreads();
    }
    if (tid == 0) partial[blockIdx.x] = s[0];
}

__global__ void scan_top_kernel(int* __restrict__ partial, int nb) {
    __shared__ int s[SCAN_BLOCK];
    int tid = threadIdx.x;
    int v = (tid < nb) ? partial[tid] : 0;
    s[tid] = v;
    __syncthreads();
    for (int off = 1; off < SCAN_BLOCK; off <<= 1) {
        int t = (tid >= off) ? s[tid - off] : 0;
        __syncthreads();
        s[tid] += t;
        __syncthreads();
    }
    if (tid < nb) partial[tid] = s[tid] - v;  // exclusive
}

__global__ void scan_final_kernel(int* __restrict__ cnt_cursor, const int* __restrict__ partial,
                                  int* __restrict__ row_ptr, int n) {
    __shared__ int s[SCAN_BLOCK];
    int tid = threadIdx.x;
    int gid = blockIdx.x * SCAN_BLOCK + tid;
    int v = (gid < n) ? cnt_cursor[gid] : 0;
    s[tid] = v;
    __syncthreads();
    for (int off = 1; off < SCAN_BLOCK; off <<= 1) {
        int t = (tid >= off) ? s[tid - off] : 0;
        __syncthreads();
        s[tid] += t;
        __syncthreads();
    }
    int excl = s[tid] - v + partial[blockIdx.x];
    if (gid < n) {
        row_ptr[gid] = excl;
        cnt_cursor[gid] = excl;
    }
    if (gid == n - 1) row_ptr[n] = excl + v;
}

// Scatter (col, val) payload directly into CSR position — no order[] indirection later.
__global__ void scatter_payload_kernel(const int* __restrict__ adj_rows, const int* __restrict__ adj_cols,
                                       const float* __restrict__ adj_vals, int nnz_a,
                                       const int* __restrict__ feat_rows, const int* __restrict__ feat_cols,
                                       const float* __restrict__ feat_vals, int nnz_x,
                                       int* __restrict__ cursor, int2* __restrict__ payload, int n_nodes) {
    int i = blockIdx.x * blockDim.x + threadIdx.x;
    int r, c;
    float v;
    int base;
    if (i < nnz_a) {
        r = adj_rows[i]; c = adj_cols[i]; v = adj_vals[i]; base = 0;
    } else if (i < nnz_a + nnz_x) {
        int j = i - nnz_a;
        r = feat_rows[j]; c = feat_cols[j]; v = feat_vals[j]; base = n_nodes;
    } else {
        return;
    }
    int p = atomicAdd(&cursor[base + r], 1);
    payload[p] = make_int2(c, __float_as_int(v));
}

// ---------- gather stages ----------

// XW[node,:] (fp16) = sum over X-row nnz of val * W[col,:]
// 32 lanes/node, float4 accum each; payload loaded coalesced, broadcast via shfl.
__global__ void gather_xw_kernel(const int* __restrict__ rp, const int2* __restrict__ payload,
                                 const float* __restrict__ W, __half* __restrict__ XW, int n) {
    int t = blockIdx.x * blockDim.x + threadIdx.x;
    int node = t >> 5;
    int lane = t & 31;
    if (node >= n) return;
    int start = rp[n + node];
    int end = rp[n + node + 1];
    float4 acc = {0.f, 0.f, 0.f, 0.f};
    const float4* W4 = (const float4*)W;
    for (int base = start; base < end; base += 32) {
        int m = end - base;
        int cnt = m < 32 ? m : 32;
        int2 pl = make_int2(0, 0);
        if (lane < cnt) pl = payload[base + lane];
        for (int j = 0; j < cnt; ++j) {
            int c = __shfl(pl.x, j, 32);
            float v = __int_as_float(__shfl(pl.y, j, 32));
            float4 w = W4[(size_t)c * 32 + lane];
            acc.x += v * w.x;
            acc.y += v * w.y;
            acc.z += v * w.z;
            acc.w += v * w.w;
        }
    }
    union { __half2 h[2]; float2 f; } u;
    u.h[0] = __floats2half2_rn(acc.x, acc.y);
    u.h[1] = __floats2half2_rn(acc.z, acc.w);
    ((float2*)XW)[(size_t)node * 32 + lane] = u.f;
}

// out[node,:] = relu( sum over A-row nnz of val * XW[col,:] ), XW fp16 -> fp32 accum
__global__ void gather_agg_relu_kernel(const int* __restrict__ rp, const int2* __restrict__ payload,
                                       const __half* __restrict__ XW, float* __restrict__ out, int n) {
    int t = blockIdx.x * blockDim.x + threadIdx.x;
    int node = t >> 5;
    int lane = t & 31;
    if (node >= n) return;
    int start = rp[node];
    int end = rp[node + 1];
    float4 acc = {0.f, 0.f, 0.f, 0.f};
    const float2* X2 = (const float2*)XW;  // 4 halves per lane
    for (int base = start; base < end; base += 32) {
        int m = end - base;
        int cnt = m < 32 ? m : 32;
        int2 pl = make_int2(0, 0);
        if (lane < cnt) pl = payload[base + lane];
        for (int j = 0; j < cnt; ++j) {
            int c = __shfl(pl.x, j, 32);
            float v = __int_as_float(__shfl(pl.y, j, 32));
            union { float2 f; __half2 h[2]; } u;
            u.f = X2[(size_t)c * 32 + lane];
            float2 a = __half22float2(u.h[0]);
            float2 b = __half22float2(u.h[1]);
            acc.x += v * a.x;
            acc.y += v * a.y;
            acc.z += v * b.x;
            acc.w += v * b.y;
        }
    }
    acc.x = fmaxf(acc.x, 0.f);
    acc.y = fmaxf(acc.y, 0.f);
    acc.z = fmaxf(acc.z, 0.f);
    acc.w = fmaxf(acc.w, 0.f);
    ((float4*)out)[(size_t)node * 32 + lane] = acc;
}

extern "C" void kernel_launch(void* const* d_in, const int* in_sizes, int n_in,
                              void* d_out, int out_size, void* d_ws, size_t ws_size,
                              hipStream_t stream) {
    const int*   feat_rows = (const int*)d_in[0];
    const int*   feat_cols = (const int*)d_in[1];
    const float* feat_vals = (const float*)d_in[2];
    const int*   adj_rows  = (const int*)d_in[3];
    const int*   adj_cols  = (const int*)d_in[4];
    const float* adj_vals  = (const float*)d_in[5];
    const float* W         = (const float*)d_in[6];
    float*       out       = (float*)d_out;

    const int nnz_x   = in_sizes[0];
    const int nnz_a   = in_sizes[3];
    const int n_nodes = out_size / OUT_DIM;
    const int n2      = 2 * n_nodes;
    const int nnz_tot = nnz_a + nnz_x;

    // ---- workspace layout ----
    char* p = (char*)d_ws;
    __half* XW   = (__half*)p;   p += (size_t)n_nodes * OUT_DIM * sizeof(__half);   // 25.6 MB
    int2* payload = (int2*)p;    p += (size_t)nnz_tot * sizeof(int2);               // 25.6 MB
    int* rp      = (int*)p;      p += (size_t)(n2 + 1) * sizeof(int);
    int* cursor  = (int*)p;      p += (size_t)n2 * sizeof(int);
    int* partial = (int*)p;      p += (size_t)SCAN_BLOCK * sizeof(int);

    const int block = 256;
    const int nb_scan = (n2 + SCAN_BLOCK - 1) / SCAN_BLOCK;
    const int grid_nnz = (nnz_tot + block - 1) / block;

    hipMemsetAsync(cursor, 0, (size_t)n2 * sizeof(int), stream);

    hist2_kernel<<<grid_nnz, block, 0, stream>>>(adj_rows, nnz_a, feat_rows, nnz_x, cursor, n_nodes);

    scan_partial_kernel<<<nb_scan, SCAN_BLOCK, 0, stream>>>(cursor, partial, n2);
    scan_top_kernel<<<1, SCAN_BLOCK, 0, stream>>>(partial, nb_scan);
    scan_final_kernel<<<nb_scan, SCAN_BLOCK, 0, stream>>>(cursor, partial, rp, n2);

    scatter_payload_kernel<<<grid_nnz, block, 0, stream>>>(adj_rows, adj_cols, adj_vals, nnz_a,
                                                           feat_rows, feat_cols, feat_vals, nnz_x,
                                                           cursor, payload, n_nodes);

    const int grid_gather = ((n_nodes * 32) + block - 1) / block;
    gather_xw_kernel<<<grid_gather, block, 0, stream>>>(rp, payload, W, XW, n_nodes);
    gather_agg_relu_kernel<<<grid_gather, block, 0, stream>>>(rp, payload, XW, out, n_nodes);
}